// Round 22
// baseline (1431.197 us; speedup 1.0000x reference)
//
#include <hip/hip_runtime.h>
#include <hip/hip_bf16.h>

#define B_ 256
#define T_ 512
#define IN_ 202
#define HID_ 100
#define K_ 19
#define NCH 32      // chunks of L=16
#define CL 16
#define MSTRIDE 368 // 361 padded

// LDS float-offsets for k_crf (dynamic shared)
#define MV_OFF   0
#define MP_OFF   (MV_OFF + NCH * MSTRIDE)      // 11776
#define TRT_OFF  (MP_OFF + NCH * MSTRIDE)      // 23552  trT[j*20+k] = tr[k][j]
#define ETL_OFF  (TRT_OFF + 380)               // ETl[j*20+k] = exp(tr[k][j])
#define BV_OFF   (ETL_OFF + 380)               // 32*20 boundary states
#define VF_OFF   (BV_OFF + 640)                // final Viterbi state (20)
#define PF_OFF   (VF_OFF + 20)                 // final logZ P (20)
#define STL_OFF  (PF_OFF + 20)
#define ENL_OFF  (STL_OFF + 20)
#define NUM_OFF  (ENL_OFF + 20)
#define KC_OFF   (NUM_OFF + 2)
#define FLT_END  (KC_OFF + 2)                  // 25036 -> pad
#define HL_OFF_B 100544                        // >= FLT_END*4, 64-aligned
#define LEN_OFF_B (HL_OFF_B + 9728)
#define CRF_LDS_B (LEN_OFF_B + 64)             // ~110.3 KB

typedef __attribute__((ext_vector_type(8))) short short8v;
typedef __attribute__((ext_vector_type(4))) float f32x4;

__device__ __forceinline__ float rl_f(float v, int l) {
  return __int_as_float(__builtin_amdgcn_readlane(__float_as_int(v), l));
}
__device__ __forceinline__ float bcast_f(float v, int l) {
  return __int_as_float(__builtin_amdgcn_ds_bpermute(l * 4, __float_as_int(v)));
}
__device__ __forceinline__ float fast_tanh(float x) {
  float t = __expf(2.f * x);
  float r = __builtin_amdgcn_rcpf(t + 1.f);
  return fmaf(-2.f, r, 1.f);
}

// ---------------- K0: split [wf;wb] (200x202) into 3 exact bf16 planes, padded to 224x224.
__global__ __launch_bounds__(256, 1) void k_wprep(
    const float* __restrict__ wf, const float* __restrict__ wb,
    unsigned short* __restrict__ w3) {
  int idx = blockIdx.x * 256 + threadIdx.x;
  if (idx >= 224 * 224) return;
  int c = idx / 224, k = idx - (idx / 224) * 224;
  float v = 0.f;
  if (k < IN_) {
    if (c < 100) v = wf[c * IN_ + k];
    else if (c < 200) v = wb[(c - 100) * IN_ + k];
  }
  unsigned u0 = __float_as_uint(v) & 0xffff0000u;
  float r1 = v - __uint_as_float(u0);
  unsigned u1 = __float_as_uint(r1) & 0xffff0000u;
  float r2 = r1 - __uint_as_float(u1);
  w3[idx] = (unsigned short)(u0 >> 16);
  w3[50176 + idx] = (unsigned short)(u1 >> 16);
  w3[100352 + idx] = (unsigned short)(__float_as_uint(r2) >> 16);
}

// ---------------- K1: pre = x . [wf;wb]^T + bias via bf16-split MFMA (round-18 proven).
__global__ __launch_bounds__(256, 2) void k_ih(
    const float* __restrict__ x, const unsigned short* __restrict__ w3,
    const float* __restrict__ bif, const float* __restrict__ bhf,
    const float* __restrict__ bib, const float* __restrict__ bhb,
    float* __restrict__ pre) {
  __shared__ float xs[128 * 36];
  __shared__ float bsum[224];
  int tid = threadIdx.x;
  int wv = tid >> 6, l = tid & 63;
  long row0 = (long)blockIdx.x * 128;
  for (int u = tid; u < 224; u += 256) {
    float bv = 0.f;
    if (u < 100) bv = bif[u] + bhf[u];
    else if (u < 200) bv = bib[u - 100] + bhb[u - 100];
    bsum[u] = bv;
  }
  int lr = l & 15;
  int kq = l >> 4;
  f32x4 acc[2][14];
#pragma unroll
  for (int m = 0; m < 2; m++)
#pragma unroll
    for (int n = 0; n < 14; n++) acc[m][n] = (f32x4){0.f, 0.f, 0.f, 0.f};
  for (int ck = 0; ck < 7; ck++) {
    int k0 = ck * 32;
    __syncthreads();
#pragma unroll
    for (int i = 0; i < 8; i++) {
      int u = tid + i * 256;
      int r = u >> 4, kp = u & 15;
      int gk = k0 + 2 * kp;
      float2 v = make_float2(0.f, 0.f);
      if (gk < IN_) v = *(const float2*)(x + (row0 + r) * IN_ + gk);
      *(float2*)(&xs[r * 36 + 2 * kp]) = v;
    }
    __syncthreads();
    short8v A0[2], A1[2], A2[2];
#pragma unroll
    for (int m = 0; m < 2; m++) {
      const float* ap = &xs[(wv * 32 + m * 16 + lr) * 36 + kq * 8];
      float4 fa = *(const float4*)(ap);
      float4 fb = *(const float4*)(ap + 4);
      float f[8] = {fa.x, fa.y, fa.z, fa.w, fb.x, fb.y, fb.z, fb.w};
#pragma unroll
      for (int j = 0; j < 8; j++) {
        unsigned u0 = __float_as_uint(f[j]) & 0xffff0000u;
        float r1 = f[j] - __uint_as_float(u0);
        unsigned u1 = __float_as_uint(r1) & 0xffff0000u;
        float r2 = r1 - __uint_as_float(u1);
        A0[m][j] = (short)(u0 >> 16);
        A1[m][j] = (short)(u1 >> 16);
        A2[m][j] = (short)(__float_as_uint(r2) >> 16);
      }
    }
#pragma unroll
    for (int n = 0; n < 14; n++) {
      int col = n * 16 + lr;
      const unsigned short* bp = w3 + (long)col * 224 + k0 + kq * 8;
      short8v B0 = *(const short8v*)(bp);
      short8v B1 = *(const short8v*)(bp + 50176);
      short8v B2 = *(const short8v*)(bp + 100352);
#pragma unroll
      for (int m = 0; m < 2; m++) {
        f32x4 c = acc[m][n];
        c = __builtin_amdgcn_mfma_f32_16x16x32_bf16(A0[m], B0, c, 0, 0, 0);
        c = __builtin_amdgcn_mfma_f32_16x16x32_bf16(A0[m], B1, c, 0, 0, 0);
        c = __builtin_amdgcn_mfma_f32_16x16x32_bf16(A1[m], B0, c, 0, 0, 0);
        c = __builtin_amdgcn_mfma_f32_16x16x32_bf16(A0[m], B2, c, 0, 0, 0);
        c = __builtin_amdgcn_mfma_f32_16x16x32_bf16(A2[m], B0, c, 0, 0, 0);
        c = __builtin_amdgcn_mfma_f32_16x16x32_bf16(A1[m], B1, c, 0, 0, 0);
        c = __builtin_amdgcn_mfma_f32_16x16x32_bf16(A1[m], B2, c, 0, 0, 0);
        c = __builtin_amdgcn_mfma_f32_16x16x32_bf16(A2[m], B1, c, 0, 0, 0);
        acc[m][n] = c;
      }
    }
  }
#pragma unroll
  for (int m = 0; m < 2; m++) {
    long rbase = row0 + wv * 32 + m * 16 + kq * 4;
#pragma unroll
    for (int n = 0; n < 13; n++) {
      int col = n * 16 + lr;
      if (col < 200) {
        float bv = bsum[col];
#pragma unroll
        for (int r = 0; r < 4; r++)
          pre[(rbase + r) * 200 + col] = acc[m][n][r] + bv;
      }
    }
  }
}

// ---------------- K2: recurrence over b; 8 waves/chain, slices {16,28,28,28},
// fast tanh, 2 barriers/step (round-17 proven).
template <int KO, int KN, bool OW>
__device__ __forceinline__ void rnn8(
    float* __restrict__ p, long step, int row, bool owns, int qidx,
    const float* __restrict__ w, float (*hb)[104], float (*ps)[104]) {
  float wr[KN];
#pragma unroll
  for (int i = 0; i < KN / 4; i++) {
    float4 w4 = *(const float4*)(w + row * HID_ + KO + 4 * i);
    wr[4 * i + 0] = w4.x; wr[4 * i + 1] = w4.y;
    wr[4 * i + 2] = w4.z; wr[4 * i + 3] = w4.w;
  }
  float a = 0.f;
  if (OW) a = p[row];
  for (int s = 0; s < B_; s++) {
    int cur = s & 1;
    float a_next = 0.f;
    if (OW && s < B_ - 1) a_next = p[step + row];
    float ac0 = OW ? a : 0.f, ac1 = 0.f, ac2 = 0.f, ac3 = 0.f;
#pragma unroll
    for (int i = 0; i < KN / 4; i++) {
      float4 h4 = *(const float4*)(&hb[cur][KO + 4 * i]);
      ac0 = fmaf(h4.x, wr[4 * i + 0], ac0);
      ac1 = fmaf(h4.y, wr[4 * i + 1], ac1);
      ac2 = fmaf(h4.z, wr[4 * i + 2], ac2);
      ac3 = fmaf(h4.w, wr[4 * i + 3], ac3);
    }
    float partial = (ac0 + ac1) + (ac2 + ac3);
    if (!OW && owns) ps[qidx][row] = partial;
    __syncthreads();
    if (OW) {
      float tot = partial + ps[0][row] + ps[1][row] + ps[2][row];
      float hnew = fast_tanh(tot);
      if (owns) {
        p[row] = hnew;
        hb[cur ^ 1][row] = hnew;
      }
    }
    __syncthreads();
    p += step;
    a = a_next;
  }
}

__global__ __launch_bounds__(512, 8) void k_rnn(
    float* __restrict__ pre,
    const float* __restrict__ whf, const float* __restrict__ whb) {
  __shared__ __align__(16) float hb[2][104];
  __shared__ __align__(16) float ps[3][104];
  int bid = blockIdx.x;
  int dir = bid >> 9;
  int t = bid & 511;
  const float* w = dir ? whb : whf;
  int tid = threadIdx.x;
  int wv = tid >> 6, lane = tid & 63;
  int grp = wv & 1;
  int kq = wv >> 1;
  int row = grp ? (64 + (lane < 36 ? lane : 35)) : lane;
  bool owns = grp ? (lane < 36) : true;
  long step = dir ? -(long)(T_ * 200) : (long)(T_ * 200);
  float* p = pre + ((long)(dir ? (B_ - 1) : 0) * T_ + t) * 200 + dir * 100;
  if (tid < 104) hb[0][tid] = 0.f;
  __syncthreads();
  if (kq == 0)      rnn8<0, 16, true >(p, step, row, owns, 0, w, hb, ps);
  else if (kq == 1) rnn8<16, 28, false>(p, step, row, owns, 0, w, hb, ps);
  else if (kq == 2) rnn8<44, 28, false>(p, step, row, owns, 1, w, hb, ps);
  else              rnn8<72, 28, false>(p, step, row, owns, 2, w, hb, ps);
}

// ---------------- K3: logits = h @ w_lin^T + b_lin ; softmax over 19. 2 rows/thread.
__global__ __launch_bounds__(256, 4) void k_lin(
    const float* __restrict__ h, const float* __restrict__ wlin,
    const float* __restrict__ blin, float* __restrict__ em) {
  int tid = threadIdx.x;
  long r0 = ((long)blockIdx.x * 256 + tid) * 2;
  const float* h0 = h + r0 * 200;
  float acc0[K_], acc1[K_];
#pragma unroll
  for (int c = 0; c < K_; c++) { float bb = blin[c]; acc0[c] = bb; acc1[c] = bb; }
  for (int kk = 0; kk < 50; kk++) {
    float4 a = *(const float4*)(h0 + 4 * kk);
    float4 b = *(const float4*)(h0 + 200 + 4 * kk);
#pragma unroll
    for (int c = 0; c < K_; c++) {
      float4 wv = *(const float4*)(wlin + c * 200 + 4 * kk);
      acc0[c] += a.x * wv.x + a.y * wv.y + a.z * wv.z + a.w * wv.w;
      acc1[c] += b.x * wv.x + b.y * wv.y + b.z * wv.z + b.w * wv.w;
    }
  }
  float mx0 = acc0[0], mx1 = acc1[0];
#pragma unroll
  for (int c = 1; c < K_; c++) { mx0 = fmaxf(mx0, acc0[c]); mx1 = fmaxf(mx1, acc1[c]); }
  float s0 = 0.f, s1 = 0.f;
#pragma unroll
  for (int c = 0; c < K_; c++) {
    acc0[c] = __expf(acc0[c] - mx0); s0 += acc0[c];
    acc1[c] = __expf(acc1[c] - mx1); s1 += acc1[c];
  }
  float i0 = 1.f / s0, i1 = 1.f / s1;
  float* e0 = em + r0 * K_;
#pragma unroll
  for (int c = 0; c < K_; c++) { e0[c] = acc0[c] * i0; e0[K_ + c] = acc1[c] * i1; }
}

// ---------------- K4: chunked-scan CRF (round-20 structure). Overflow fixes:
// (1) pr normalized BEFORE the combine dot (chunk matrices ~e^62);
// (2) pr normalized EACH TAIL STEP too (P enters tail ~e^28, tail grows 57x/step).
__global__ __launch_bounds__(512, 1) void k_crf(
    const float* __restrict__ em, const int* __restrict__ y,
    const float* __restrict__ st_g, const float* __restrict__ en_g,
    const float* __restrict__ tr_g,
    float* __restrict__ part, int* __restrict__ cnt,
    float* __restrict__ out) {
  extern __shared__ __align__(16) float S[];
  unsigned char* hl = (unsigned char*)S + HL_OFF_B;
  int* lenp = (int*)((char*)S + LEN_OFF_B);
  int b = blockIdx.x;
  int tid = threadIdx.x;
  int wv = tid >> 6, lane = tid & 63;
  const float* eb = em + (long)b * T_ * K_;
  const int* yb = y + (long)b * T_;
  // ---- stage tables + len
  if (tid < 380) {
    int j = tid / 20, k = tid - (tid / 20) * 20;
    float tv = (k < 19) ? tr_g[k * 19 + j] : 0.f;
    S[TRT_OFF + tid] = tv;
    S[ETL_OFF + tid] = (k < 19) ? __expf(tv) : 0.f;
  }
  if (tid >= 384 && tid < 384 + K_) {
    int i = tid - 384;
    S[STL_OFF + i] = st_g[i];
    S[ENL_OFF + i] = en_g[i];
  }
  if (tid == 0) *lenp = T_;
  __syncthreads();
  if (yb[tid] == -1) atomicMin(lenp, tid);
  __syncthreads();
  int len = *lenp;                 // >= 1
  int nf = (len - 1) >> 4;         // full chunks
  int rr_ = (len - 1) - (nf << 4); // partial steps

  int sg = (lane >= 19) + (lane >= 38);
  bool gact = lane < 57;
  int li = lane - sg * 19;
  int gid = wv * 3 + sg;           // 0..23

  // ---- phase 1a: Viterbi chunk matrices (chunks 0..30)
  for (int rnd = 0; rnd < 2; rnd++) {
    int c = gid + 24 * rnd;
    if (gact && c < NCH - 1) {
      int t0 = CL * c + 1;
      float m[19], e_[19];
#pragma unroll
      for (int j = 0; j < 19; j++) e_[j] = eb[t0 * K_ + j];
#pragma unroll
      for (int j = 0; j < 19; j++) m[j] = S[TRT_OFF + j * 20 + li] + e_[j];
      for (int s = 1; s < CL; s++) {
        int t = t0 + s;
#pragma unroll
        for (int j = 0; j < 19; j++) e_[j] = eb[t * K_ + j];
        float nm[19];
#pragma unroll
        for (int j = 0; j < 19; j++) {
          const float* tc = &S[TRT_OFF + j * 20];
          float best = m[0] + tc[0];
#pragma unroll
          for (int k = 1; k < 19; k++) best = fmaxf(best, m[k] + tc[k]);
          nm[j] = best + e_[j];
        }
#pragma unroll
        for (int j = 0; j < 19; j++) m[j] = nm[j];
      }
#pragma unroll
      for (int j = 0; j < 19; j++) S[MV_OFF + c * MSTRIDE + li * 19 + j] = m[j];
    }
  }
  __syncthreads();
  // ---- phase 1b: logZ chunk matrices (prob space; entries <= ~e^62)
  for (int rnd = 0; rnd < 2; rnd++) {
    int c = gid + 24 * rnd;
    if (gact && c < NCH - 1) {
      int t0 = CL * c + 1;
      float m[19], ee[19];
#pragma unroll
      for (int j = 0; j < 19; j++) ee[j] = __expf(eb[t0 * K_ + j]);
#pragma unroll
      for (int j = 0; j < 19; j++) m[j] = S[ETL_OFF + j * 20 + li] * ee[j];
      for (int s = 1; s < CL; s++) {
        int t = t0 + s;
#pragma unroll
        for (int j = 0; j < 19; j++) ee[j] = __expf(eb[t * K_ + j]);
        float nm[19];
#pragma unroll
        for (int j = 0; j < 19; j++) {
          const float* ec = &S[ETL_OFF + j * 20];
          float a0 = 0.f, a1 = 0.f, a2 = 0.f, a3 = 0.f;
#pragma unroll
          for (int k = 0; k < 19; k++) {
            if ((k & 3) == 0)      a0 = fmaf(m[k], ec[k], a0);
            else if ((k & 3) == 1) a1 = fmaf(m[k], ec[k], a1);
            else if ((k & 3) == 2) a2 = fmaf(m[k], ec[k], a2);
            else                   a3 = fmaf(m[k], ec[k], a3);
          }
          nm[j] = ((a0 + a1) + (a2 + a3)) * ee[j];
        }
#pragma unroll
        for (int j = 0; j < 19; j++) m[j] = nm[j];
      }
#pragma unroll
      for (int j = 0; j < 19; j++) S[MP_OFF + c * MSTRIDE + li * 19 + j] = m[j];
    }
  }
  __syncthreads();
  // ---- scan phase
  if (wv == 0) {
    // Viterbi boundary scan (additive, bounded — no overflow risk)
    float Bc = 0.f;
    if (lane < K_) Bc = S[STL_OFF + lane] + eb[lane];
    for (int c = 0; c < nf; c++) {
      if (lane < K_) S[BV_OFF + c * 20 + lane] = Bc;
      float vr[19];
#pragma unroll
      for (int i = 0; i < 19; i++) vr[i] = bcast_f(Bc, i);
      if (lane < K_) {
        const float* mc = &S[MV_OFF + c * MSTRIDE];
        float best = vr[0] + mc[lane];
#pragma unroll
        for (int i = 1; i < 19; i++) best = fmaxf(best, vr[i] + mc[i * 19 + lane]);
        Bc = best;
      }
    }
    if (lane < K_) {
      S[BV_OFF + nf * 20 + lane] = Bc;
      if (rr_ == 0) S[VF_OFF + lane] = Bc;
    }
  } else if (wv == 1) {
    // logZ scan: normalize pr BEFORE every dot (combine AND tail steps)
    float P = 0.f;
    if (lane < K_) P = __expf(S[STL_OFF + lane] + eb[lane]);
    int kc = 0;
    for (int c = 0; c < nf; c++) {
      float pr[19];
#pragma unroll
      for (int i = 0; i < 19; i++) pr[i] = bcast_f(P, i);
      unsigned pb = __float_as_uint(pr[0]);
      int ex = (int)((pb >> 23) & 0xff);
      float scale = __uint_as_float((unsigned)(254 - ex) << 23);
      kc += ex - 127;
#pragma unroll
      for (int i = 0; i < 19; i++) pr[i] *= scale;  // pr now O(1)
      if (lane < K_) {
        const float* mc = &S[MP_OFF + c * MSTRIDE];
        float a0 = 0.f, a1 = 0.f, a2 = 0.f, a3 = 0.f;
#pragma unroll
        for (int i = 0; i < 19; i++) {
          float mv = mc[i * 19 + lane];
          if ((i & 3) == 0)      a0 = fmaf(pr[i], mv, a0);
          else if ((i & 3) == 1) a1 = fmaf(pr[i], mv, a1);
          else if ((i & 3) == 2) a2 = fmaf(pr[i], mv, a2);
          else                   a3 = fmaf(pr[i], mv, a3);
        }
        P = (a0 + a1) + (a2 + a3);  // <= ~1e29, safe
      }
    }
    for (int s = 0; s < rr_; s++) {
      int t = (nf << 4) + 1 + s;
      float pr[19];
#pragma unroll
      for (int i = 0; i < 19; i++) pr[i] = bcast_f(P, i);
      unsigned pb = __float_as_uint(pr[0]);
      int ex = (int)((pb >> 23) & 0xff);
      float scale = __uint_as_float((unsigned)(254 - ex) << 23);
      kc += ex - 127;
#pragma unroll
      for (int i = 0; i < 19; i++) pr[i] *= scale;  // tail renorm (fix #2)
      if (lane < K_) {
        float ee = __expf(eb[t * K_ + lane]);
        const float* ec = &S[ETL_OFF + lane * 20];
        float a0 = 0.f, a1 = 0.f, a2 = 0.f, a3 = 0.f;
#pragma unroll
        for (int i = 0; i < 19; i++) {
          if ((i & 3) == 0)      a0 = fmaf(pr[i], ec[i], a0);
          else if ((i & 3) == 1) a1 = fmaf(pr[i], ec[i], a1);
          else if ((i & 3) == 2) a2 = fmaf(pr[i], ec[i], a2);
          else                   a3 = fmaf(pr[i], ec[i], a3);
        }
        P = ((a0 + a1) + (a2 + a3)) * ee;
      }
    }
    if (lane < K_) S[PF_OFF + lane] = P;
    if (lane == 0) *(int*)&S[KC_OFF] = kc;
  } else if (wv == 2) {
    // gold-path score (parallel gather)
    float gacc = 0.f;
    for (int t = 1 + lane; t < len; t += 64) {
      int yp = yb[t - 1], yc = yb[t];
      gacc += S[TRT_OFF + yc * 20 + yp] + eb[t * K_ + yc];
    }
#pragma unroll
    for (int off = 32; off; off >>= 1) gacc += __shfl_xor(gacc, off, 64);
    if (lane == 0) {
      int y0 = yb[0], yl = yb[len - 1];
      S[NUM_OFF] = S[STL_OFF + y0] + eb[y0] + gacc + S[ENL_OFF + yl];
    }
  } else if (wv == 3) {
    float* ob = out + 1 + (long)b * T_;
    for (int u = lane; u < T_; u += 64)
      if (u >= len) ob[u] = -1.f;
  }
  __syncthreads();
  // ---- replay (hist) + logZ finalize
  if (wv == 0) {
    int c = lane;
    if (c <= nf && c < NCH) {
      int nst = (c < nf) ? CL : rr_;
      if (nst > 0) {
        float v[19];
#pragma unroll
        for (int k = 0; k < 19; k++) v[k] = S[BV_OFF + c * 20 + k];
        for (int s = 0; s < nst; s++) {
          int t = (c << 4) + 1 + s;
          float e_[19];
#pragma unroll
          for (int j = 0; j < 19; j++) e_[j] = eb[t * K_ + j];
          float nv[19];
#pragma unroll
          for (int j = 0; j < 19; j++) {
            const float* tc = &S[TRT_OFF + j * 20];
            float best = v[0] + tc[0];
            int bi = 0;
#pragma unroll
            for (int k = 1; k < 19; k++) {
              float cd = v[k] + tc[k];
              if (cd > best) { best = cd; bi = k; }
            }
            hl[(t - 1) * K_ + j] = (unsigned char)bi;
            nv[j] = best + e_[j];
          }
#pragma unroll
          for (int j = 0; j < 19; j++) v[j] = nv[j];
        }
        if (c == nf) {
#pragma unroll
          for (int k = 0; k < 19; k++) S[VF_OFF + k] = v[k];
        }
      }
    }
  } else if (wv == 1) {
    if (lane == 0) {
      int kc = *(int*)&S[KC_OFF];
      float sm = 0.f;
#pragma unroll
      for (int i = 0; i < 19; i++) sm += S[PF_OFF + i] * __expf(S[ENL_OFF + i]);
      part[b] = __logf(sm) + (float)kc * 0.6931471805599453f - S[NUM_OFF];
    }
  }
  __syncthreads();
  // ---- backtrack + labels (wv0) ; deterministic loss reduce (wv1)
  if (wv == 0) {
    float bb = S[VF_OFF + 0] + S[ENL_OFF + 0];
    int aa = 0;
#pragma unroll
    for (int i = 1; i < 19; i++) {
      float cd = S[VF_OFF + i] + S[ENL_OFF + i];
      if (cd > bb) { bb = cd; aa = i; }
    }
    float* ob = out + 1 + (long)b * T_;
    int tag = aa;
    if (lane == 0) ob[len - 1] = (float)tag;
    bool act = lane < K_;
    int vc = (act && len >= 2) ? (int)hl[(len - 2) * K_ + lane] : 0;
    for (int ti = len - 2; ti >= 0; ti--) {
      int vn = 0;
      if (ti > 0 && act) vn = (int)hl[(ti - 1) * K_ + lane];
      int ts = __builtin_amdgcn_readfirstlane(tag);
      tag = __builtin_amdgcn_readlane(vc, ts);
      if (lane == 0) ob[ti] = (float)tag;
      vc = vn;
    }
  } else if (wv == 1) {
    int old = -1;
    if (lane == 0) { __threadfence(); old = atomicAdd(cnt, 1); }
    old = __shfl(old, 0, 64);
    if (old == B_ - 1) {
      __threadfence();
      float s = 0.f;
      for (int u = lane; u < B_; u += 64) s += part[u];
#pragma unroll
      for (int off = 32; off; off >>= 1) s += __shfl_xor(s, off, 64);
      if (lane == 0) out[0] = s;
    }
  }
}

extern "C" void kernel_launch(void* const* d_in, const int* in_sizes, int n_in,
                              void* d_out, int out_size, void* d_ws, size_t ws_size,
                              hipStream_t stream) {
  const float* x      = (const float*)d_in[0];
  const int*   y      = (const int*)d_in[1];
  const float* w_ih_f = (const float*)d_in[2];
  const float* w_hh_f = (const float*)d_in[3];
  const float* b_ih_f = (const float*)d_in[4];
  const float* b_hh_f = (const float*)d_in[5];
  const float* w_ih_b = (const float*)d_in[6];
  const float* w_hh_b = (const float*)d_in[7];
  const float* b_ih_b = (const float*)d_in[8];
  const float* b_hh_b = (const float*)d_in[9];
  const float* w_lin  = (const float*)d_in[10];
  const float* b_lin  = (const float*)d_in[11];
  const float* st     = (const float*)d_in[12];
  const float* en     = (const float*)d_in[13];
  const float* trans  = (const float*)d_in[14];

  char* ws = (char*)d_ws;
  const size_t PRE_OFF  = 0;                          // 131072*200*4 = 104857600
  const size_t EM_OFF   = 104857600;                  // 131072*19*4  = 9961472
  const size_t PART_OFF = EM_OFF + 9961472;           // 1024
  const size_t CNT_OFF  = PART_OFF + 1024;            // 4
  float* PRE  = (float*)(ws + PRE_OFF);
  float* EM   = (float*)(ws + EM_OFF);
  float* PART = (float*)(ws + PART_OFF);
  int*   CNT  = (int*)(ws + CNT_OFF);
  unsigned short* W3 = (unsigned short*)(ws + EM_OFF);  // consumed before k_lin writes EM
  float* out  = (float*)d_out;

  hipFuncSetAttribute((const void*)k_crf,
                      hipFuncAttributeMaxDynamicSharedMemorySize, CRF_LDS_B);
  hipMemsetAsync((void*)CNT, 0, sizeof(int), stream);
  k_wprep<<<196, 256, 0, stream>>>(w_ih_f, w_ih_b, W3);
  k_ih<<<1024, 256, 0, stream>>>(x, W3, b_ih_f, b_hh_f, b_ih_b, b_hh_b, PRE);
  k_rnn<<<1024, 512, 0, stream>>>(PRE, w_hh_f, w_hh_b);
  k_lin<<<256, 256, 0, stream>>>(PRE, w_lin, b_lin, EM);
  k_crf<<<256, 512, CRF_LDS_B, stream>>>(EM, y, st, en, trans, PART, CNT, out);
}

// Round 23
// 578.206 us; speedup vs baseline: 2.4752x; 2.4752x over previous
//
#include <hip/hip_runtime.h>
#include <hip/hip_bf16.h>

#define B_ 256
#define T_ 512
#define IN_ 202
#define HID_ 100
#define K_ 19

typedef __attribute__((ext_vector_type(8))) short short8v;
typedef __attribute__((ext_vector_type(4))) float f32x4;

__device__ __forceinline__ float rl_f(float v, int l) {
  return __int_as_float(__builtin_amdgcn_readlane(__float_as_int(v), l));
}
// register->register broadcast of lane l via LDS crossbar (no storage, no SGPR hazard)
__device__ __forceinline__ float bcast_f(float v, int l) {
  return __int_as_float(__builtin_amdgcn_ds_bpermute(l * 4, __float_as_int(v)));
}
// tanh(x) = 1 - 2/(exp(2x)+1): 5 instrs vs ~25 for libm; exact saturation at +-1.
__device__ __forceinline__ float fast_tanh(float x) {
  float t = __expf(2.f * x);
  float r = __builtin_amdgcn_rcpf(t + 1.f);
  return fmaf(-2.f, r, 1.f);
}

// ---------------- K0: split [wf;wb] (200x202) into 3 exact bf16 planes, padded to 224x224.
__global__ __launch_bounds__(256, 1) void k_wprep(
    const float* __restrict__ wf, const float* __restrict__ wb,
    unsigned short* __restrict__ w3) {
  int idx = blockIdx.x * 256 + threadIdx.x;
  if (idx >= 224 * 224) return;
  int c = idx / 224, k = idx - (idx / 224) * 224;
  float v = 0.f;
  if (k < IN_) {
    if (c < 100) v = wf[c * IN_ + k];
    else if (c < 200) v = wb[(c - 100) * IN_ + k];
  }
  unsigned u0 = __float_as_uint(v) & 0xffff0000u;
  float r1 = v - __uint_as_float(u0);
  unsigned u1 = __float_as_uint(r1) & 0xffff0000u;
  float r2 = r1 - __uint_as_float(u1);
  w3[idx] = (unsigned short)(u0 >> 16);
  w3[50176 + idx] = (unsigned short)(u1 >> 16);
  w3[100352 + idx] = (unsigned short)(__float_as_uint(r2) >> 16);
}

// ---------------- K1: pre = x . [wf;wb]^T + bias via bf16-split MFMA.
// SINGLE PASS over x: 1024 blocks x 128 rows; wave owns 32 rows (2 m-tiles)
// x ALL 14 n-tiles. acc[2][14] = 112 VGPR. x staged once per K-chunk.
__global__ __launch_bounds__(256, 2) void k_ih(
    const float* __restrict__ x, const unsigned short* __restrict__ w3,
    const float* __restrict__ bif, const float* __restrict__ bhf,
    const float* __restrict__ bib, const float* __restrict__ bhb,
    float* __restrict__ pre) {
  __shared__ float xs[128 * 36];
  __shared__ float bsum[224];
  int tid = threadIdx.x;
  int wv = tid >> 6, l = tid & 63;
  long row0 = (long)blockIdx.x * 128;
  for (int u = tid; u < 224; u += 256) {
    float bv = 0.f;
    if (u < 100) bv = bif[u] + bhf[u];
    else if (u < 200) bv = bib[u - 100] + bhb[u - 100];
    bsum[u] = bv;
  }
  int lr = l & 15;
  int kq = l >> 4;
  f32x4 acc[2][14];
#pragma unroll
  for (int m = 0; m < 2; m++)
#pragma unroll
    for (int n = 0; n < 14; n++) acc[m][n] = (f32x4){0.f, 0.f, 0.f, 0.f};
  for (int ck = 0; ck < 7; ck++) {
    int k0 = ck * 32;
    __syncthreads();
#pragma unroll
    for (int i = 0; i < 8; i++) {
      int u = tid + i * 256;
      int r = u >> 4, kp = u & 15;
      int gk = k0 + 2 * kp;
      float2 v = make_float2(0.f, 0.f);
      if (gk < IN_) v = *(const float2*)(x + (row0 + r) * IN_ + gk);
      *(float2*)(&xs[r * 36 + 2 * kp]) = v;
    }
    __syncthreads();
    // A fragments (2 m-tiles), exact 3-way bf16 split in-register
    short8v A0[2], A1[2], A2[2];
#pragma unroll
    for (int m = 0; m < 2; m++) {
      const float* ap = &xs[(wv * 32 + m * 16 + lr) * 36 + kq * 8];
      float4 fa = *(const float4*)(ap);
      float4 fb = *(const float4*)(ap + 4);
      float f[8] = {fa.x, fa.y, fa.z, fa.w, fb.x, fb.y, fb.z, fb.w};
#pragma unroll
      for (int j = 0; j < 8; j++) {
        unsigned u0 = __float_as_uint(f[j]) & 0xffff0000u;
        float r1 = f[j] - __uint_as_float(u0);
        unsigned u1 = __float_as_uint(r1) & 0xffff0000u;
        float r2 = r1 - __uint_as_float(u1);
        A0[m][j] = (short)(u0 >> 16);
        A1[m][j] = (short)(u1 >> 16);
        A2[m][j] = (short)(__float_as_uint(r2) >> 16);
      }
    }
#pragma unroll
    for (int n = 0; n < 14; n++) {
      int col = n * 16 + lr;
      const unsigned short* bp = w3 + (long)col * 224 + k0 + kq * 8;
      short8v B0 = *(const short8v*)(bp);
      short8v B1 = *(const short8v*)(bp + 50176);
      short8v B2 = *(const short8v*)(bp + 100352);
#pragma unroll
      for (int m = 0; m < 2; m++) {
        f32x4 c = acc[m][n];
        c = __builtin_amdgcn_mfma_f32_16x16x32_bf16(A0[m], B0, c, 0, 0, 0);
        c = __builtin_amdgcn_mfma_f32_16x16x32_bf16(A0[m], B1, c, 0, 0, 0);
        c = __builtin_amdgcn_mfma_f32_16x16x32_bf16(A1[m], B0, c, 0, 0, 0);
        c = __builtin_amdgcn_mfma_f32_16x16x32_bf16(A0[m], B2, c, 0, 0, 0);
        c = __builtin_amdgcn_mfma_f32_16x16x32_bf16(A2[m], B0, c, 0, 0, 0);
        c = __builtin_amdgcn_mfma_f32_16x16x32_bf16(A1[m], B1, c, 0, 0, 0);
        c = __builtin_amdgcn_mfma_f32_16x16x32_bf16(A1[m], B2, c, 0, 0, 0);
        c = __builtin_amdgcn_mfma_f32_16x16x32_bf16(A2[m], B1, c, 0, 0, 0);
        acc[m][n] = c;
      }
    }
  }
#pragma unroll
  for (int m = 0; m < 2; m++) {
    long rbase = row0 + wv * 32 + m * 16 + kq * 4;
#pragma unroll
    for (int n = 0; n < 13; n++) {  // n=13 -> cols 208..223 all padding
      int col = n * 16 + lr;
      if (col < 200) {
        float bv = bsum[col];
#pragma unroll
        for (int r = 0; r < 4; r++)
          pre[(rbase + r) * 200 + col] = acc[m][n][r] + bv;
      }
    }
  }
}

// ---------------- K2: recurrence over b (256 steps); 8 waves per (t,dir) chain.
// K-slices BALANCED {16,28,28,28}; fast tanh; 2 barriers/step.
template <int KO, int KN, bool OW>
__device__ __forceinline__ void rnn8(
    float* __restrict__ p, long step, int row, bool owns, int qidx,
    const float* __restrict__ w, float (*hb)[104], float (*ps)[104]) {
  float wr[KN];
#pragma unroll
  for (int i = 0; i < KN / 4; i++) {
    float4 w4 = *(const float4*)(w + row * HID_ + KO + 4 * i);
    wr[4 * i + 0] = w4.x; wr[4 * i + 1] = w4.y;
    wr[4 * i + 2] = w4.z; wr[4 * i + 3] = w4.w;
  }
  float a = 0.f;
  if (OW) a = p[row];
  for (int s = 0; s < B_; s++) {
    int cur = s & 1;
    float a_next = 0.f;
    if (OW && s < B_ - 1) a_next = p[step + row];
    float ac0 = OW ? a : 0.f, ac1 = 0.f, ac2 = 0.f, ac3 = 0.f;
#pragma unroll
    for (int i = 0; i < KN / 4; i++) {
      float4 h4 = *(const float4*)(&hb[cur][KO + 4 * i]);  // uniform -> broadcast
      ac0 = fmaf(h4.x, wr[4 * i + 0], ac0);
      ac1 = fmaf(h4.y, wr[4 * i + 1], ac1);
      ac2 = fmaf(h4.z, wr[4 * i + 2], ac2);
      ac3 = fmaf(h4.w, wr[4 * i + 3], ac3);
    }
    float partial = (ac0 + ac1) + (ac2 + ac3);
    if (!OW && owns) ps[qidx][row] = partial;
    __syncthreads();
    if (OW) {
      float tot = partial + ps[0][row] + ps[1][row] + ps[2][row];
      float hnew = fast_tanh(tot);
      if (owns) {
        p[row] = hnew;
        hb[cur ^ 1][row] = hnew;
      }
    }
    __syncthreads();
    p += step;
    a = a_next;
  }
}

__global__ __launch_bounds__(512, 8) void k_rnn(
    float* __restrict__ pre,
    const float* __restrict__ whf, const float* __restrict__ whb) {
  __shared__ __align__(16) float hb[2][104];
  __shared__ __align__(16) float ps[3][104];
  int bid = blockIdx.x;
  int dir = bid >> 9;
  int t = bid & 511;
  const float* w = dir ? whb : whf;
  int tid = threadIdx.x;
  int wv = tid >> 6, lane = tid & 63;
  int grp = wv & 1;     // 0: rows 0..63, 1: rows 64..99
  int kq = wv >> 1;     // K slice 0..3 (0 = owner)
  int row = grp ? (64 + (lane < 36 ? lane : 35)) : lane;
  bool owns = grp ? (lane < 36) : true;
  long step = dir ? -(long)(T_ * 200) : (long)(T_ * 200);
  float* p = pre + ((long)(dir ? (B_ - 1) : 0) * T_ + t) * 200 + dir * 100;
  if (tid < 104) hb[0][tid] = 0.f;
  __syncthreads();
  if (kq == 0)      rnn8<0, 16, true >(p, step, row, owns, 0, w, hb, ps);
  else if (kq == 1) rnn8<16, 28, false>(p, step, row, owns, 0, w, hb, ps);
  else if (kq == 2) rnn8<44, 28, false>(p, step, row, owns, 1, w, hb, ps);
  else              rnn8<72, 28, false>(p, step, row, owns, 2, w, hb, ps);
}

// ---------------- K3: logits = h @ w_lin^T + b_lin ; softmax over 19. 2 rows/thread.
__global__ __launch_bounds__(256, 4) void k_lin(
    const float* __restrict__ h, const float* __restrict__ wlin,
    const float* __restrict__ blin, float* __restrict__ em) {
  int tid = threadIdx.x;
  long r0 = ((long)blockIdx.x * 256 + tid) * 2;
  const float* h0 = h + r0 * 200;
  float acc0[K_], acc1[K_];
#pragma unroll
  for (int c = 0; c < K_; c++) { float bb = blin[c]; acc0[c] = bb; acc1[c] = bb; }
  for (int kk = 0; kk < 50; kk++) {
    float4 a = *(const float4*)(h0 + 4 * kk);
    float4 b = *(const float4*)(h0 + 200 + 4 * kk);
#pragma unroll
    for (int c = 0; c < K_; c++) {
      float4 wv = *(const float4*)(wlin + c * 200 + 4 * kk);  // uniform -> s_load
      acc0[c] += a.x * wv.x + a.y * wv.y + a.z * wv.z + a.w * wv.w;
      acc1[c] += b.x * wv.x + b.y * wv.y + b.z * wv.z + b.w * wv.w;
    }
  }
  float mx0 = acc0[0], mx1 = acc1[0];
#pragma unroll
  for (int c = 1; c < K_; c++) { mx0 = fmaxf(mx0, acc0[c]); mx1 = fmaxf(mx1, acc1[c]); }
  float s0 = 0.f, s1 = 0.f;
#pragma unroll
  for (int c = 0; c < K_; c++) {
    acc0[c] = __expf(acc0[c] - mx0); s0 += acc0[c];
    acc1[c] = __expf(acc1[c] - mx1); s1 += acc1[c];
  }
  float i0 = 1.f / s0, i1 = 1.f / s1;
  float* e0 = em + r0 * K_;
#pragma unroll
  for (int c = 0; c < K_; c++) { e0[c] = acc0[c] * i0; e0[K_ + c] = acc1[c] * i1; }
}

// ---------------- K4: 2 waves per b; bpermute state broadcast. wave0: logZ in
// scaled probability space (exact power-of-2 renorm per step) + parallel gold
// gather. wave1: Viterbi forward + backtrack. (Best measured: ~199 us.)
__global__ __launch_bounds__(128, 1) void k_crf(
    const float* __restrict__ em, const int* __restrict__ y,
    const float* __restrict__ st_g, const float* __restrict__ en_g,
    const float* __restrict__ tr_g,
    float* __restrict__ part, int* __restrict__ cnt,
    float* __restrict__ out) {
  __shared__ __align__(16) float es[T_ * K_];
  __shared__ int ys[T_];
  __shared__ float trs[K_ * K_];
  __shared__ float st[K_], en[K_];
  __shared__ unsigned char hl[511 * K_ + 13];
  int b = blockIdx.x;
  int tid = threadIdx.x;
  int wv = tid >> 6, lane = tid & 63;
  const float4* eb4 = (const float4*)(em + (long)b * T_ * K_);
  for (int u = tid; u < T_ * K_ / 4; u += 128) ((float4*)es)[u] = eb4[u];
  for (int u = tid; u < T_; u += 128) ys[u] = y[b * T_ + u];
  for (int u = tid; u < K_ * K_; u += 128) trs[u] = tr_g[u];
  if (tid < K_) { st[tid] = st_g[tid]; en[tid] = en_g[tid]; }
  __syncthreads();
  int lmin = T_;
  for (int u = lane; u < T_; u += 64)
    if (ys[u] == -1 && u < lmin) lmin = u;
#pragma unroll
  for (int off = 32; off; off >>= 1) {
    int o = __shfl_xor(lmin, off, 64);
    lmin = lmin < o ? lmin : o;
  }
  int len = lmin;  // >= 1

  int jj = lane < K_ ? lane : K_ - 1;
  bool act = lane < K_;
  float enr[20];
#pragma unroll
  for (int q = 0; q < 5; q++) {
    float4 e4 = (q < 4) ? *(const float4*)(&en[4 * q])
                        : make_float4(en[16], en[17], en[18], -1e30f);
    enr[4 * q] = e4.x; enr[4 * q + 1] = e4.y; enr[4 * q + 2] = e4.z; enr[4 * q + 3] = e4.w;
  }

  if (wv == 0) {
    float gacc = 0.f;
    for (int t = 1 + lane; t < len; t += 64)
      gacc += trs[ys[t - 1] * K_ + ys[t]] + es[t * K_ + ys[t]];
#pragma unroll
    for (int off = 32; off; off >>= 1) gacc += __shfl_xor(gacc, off, 64);
    int y0 = ys[0], ylast = ys[len - 1];
    float num = st[y0] + es[y0] + gacc + en[ylast];
    float Ecol[K_];
#pragma unroll
    for (int i = 0; i < K_; i++) Ecol[i] = __expf(trs[i * K_ + jj]);
    float P = __expf(st[jj] + es[jj]);
    int kacc = 0;
    float ee = __expf(es[K_ + jj]);
    for (int t = 1; t < len; t++) {
      float pr[K_];
#pragma unroll
      for (int i = 0; i < K_; i++) pr[i] = bcast_f(P, i);
      int tn = (t + 1 < T_) ? t + 1 : T_ - 1;
      float e_next = es[tn * K_ + jj];
      unsigned pb = __float_as_uint(pr[0]);
      int ex = (int)((pb >> 23) & 0xff);
      float scale = __uint_as_float((unsigned)(254 - ex) << 23);
      kacc += ex - 127;
      float a0 = 0.f, a1 = 0.f, a2 = 0.f, a3 = 0.f;
#pragma unroll
      for (int i = 0; i < K_; i++) {
        if ((i & 3) == 0)      a0 = fmaf(pr[i], Ecol[i], a0);
        else if ((i & 3) == 1) a1 = fmaf(pr[i], Ecol[i], a1);
        else if ((i & 3) == 2) a2 = fmaf(pr[i], Ecol[i], a2);
        else                   a3 = fmaf(pr[i], Ecol[i], a3);
      }
      P = ((((a0 + a1) + (a2 + a3)) * ee)) * scale;
      ee = __expf(e_next);
    }
    {
      float pr[K_];
#pragma unroll
      for (int i = 0; i < K_; i++) pr[i] = bcast_f(P, i);
      float sm = 0.f;
#pragma unroll
      for (int i = 0; i < K_; i++) sm += pr[i] * __expf(enr[i]);
      if (lane == 0) part[b] = __logf(sm) + (float)kacc * 0.6931471805599453f - num;
    }
    int old = -1;
    if (lane == 0) { __threadfence(); old = atomicAdd(cnt, 1); }
    old = __shfl(old, 0, 64);
    if (old == B_ - 1) {
      __threadfence();
      float s = 0.f;
      for (int u = lane; u < B_; u += 64) s += part[u];
#pragma unroll
      for (int off = 32; off; off >>= 1) s += __shfl_xor(s, off, 64);
      if (lane == 0) out[0] = s;
    }
  } else {
    float Tt[K_];
#pragma unroll
    for (int i = 0; i < K_; i++) Tt[i] = trs[i * K_ + jj];
    float V = st[jj] + es[jj];
    float e = es[K_ + jj];
    for (int t = 1; t < len; t++) {
      float vr[K_];
#pragma unroll
      for (int i = 0; i < K_; i++) vr[i] = bcast_f(V, i);
      int tn = (t + 1 < T_) ? t + 1 : T_ - 1;
      float e_next = es[tn * K_ + jj];
      float b0 = -1e30f, b1 = -1e30f, b2 = -1e30f, b3 = -1e30f;
      int a0 = 0, a1 = 5, a2 = 10, a3 = 15;
#pragma unroll
      for (int i = 0; i < 5; i++)  { float c = vr[i] + Tt[i]; if (c > b0) { b0 = c; a0 = i; } }
#pragma unroll
      for (int i = 5; i < 10; i++) { float c = vr[i] + Tt[i]; if (c > b1) { b1 = c; a1 = i; } }
#pragma unroll
      for (int i = 10; i < 15; i++){ float c = vr[i] + Tt[i]; if (c > b2) { b2 = c; a2 = i; } }
#pragma unroll
      for (int i = 15; i < 19; i++){ float c = vr[i] + Tt[i]; if (c > b3) { b3 = c; a3 = i; } }
      if (b1 > b0) { b0 = b1; a0 = a1; }
      if (b2 > b0) { b0 = b2; a0 = a2; }
      if (b3 > b0) { b0 = b3; a0 = a3; }
      if (act) hl[(t - 1) * K_ + lane] = (unsigned char)a0;
      V = b0 + e;
      e = e_next;
    }
    int aa;
    {
      float vr[K_];
#pragma unroll
      for (int i = 0; i < K_; i++) vr[i] = bcast_f(V, i);
      float bb = vr[0] + enr[0]; aa = 0;
#pragma unroll
      for (int i = 1; i < K_; i++) {
        float c = vr[i] + enr[i];
        if (c > bb) { bb = c; aa = i; }
      }
    }
    float* ob = out + 1 + (long)b * T_;
    for (int u = lane; u < T_; u += 64)
      if (u >= len) ob[u] = -1.f;
    int tag = aa;
    if (lane == 0) ob[len - 1] = (float)tag;
    int vc = (act && len >= 2) ? (int)hl[(len - 2) * K_ + lane] : 0;
    for (int ti = len - 2; ti >= 0; ti--) {
      int vn = 0;
      if (ti > 0 && act) vn = (int)hl[(ti - 1) * K_ + lane];
      int ts = __builtin_amdgcn_readfirstlane(tag);
      tag = __builtin_amdgcn_readlane(vc, ts);
      if (lane == 0) ob[ti] = (float)tag;
      vc = vn;
    }
  }
}

extern "C" void kernel_launch(void* const* d_in, const int* in_sizes, int n_in,
                              void* d_out, int out_size, void* d_ws, size_t ws_size,
                              hipStream_t stream) {
  const float* x      = (const float*)d_in[0];
  const int*   y      = (const int*)d_in[1];
  const float* w_ih_f = (const float*)d_in[2];
  const float* w_hh_f = (const float*)d_in[3];
  const float* b_ih_f = (const float*)d_in[4];
  const float* b_hh_f = (const float*)d_in[5];
  const float* w_ih_b = (const float*)d_in[6];
  const float* w_hh_b = (const float*)d_in[7];
  const float* b_ih_b = (const float*)d_in[8];
  const float* b_hh_b = (const float*)d_in[9];
  const float* w_lin  = (const float*)d_in[10];
  const float* b_lin  = (const float*)d_in[11];
  const float* st     = (const float*)d_in[12];
  const float* en     = (const float*)d_in[13];
  const float* trans  = (const float*)d_in[14];

  char* ws = (char*)d_ws;
  const size_t PRE_OFF  = 0;                          // 131072*200*4 = 104857600
  const size_t EM_OFF   = 104857600;                  // 131072*19*4  = 9961472
  const size_t PART_OFF = EM_OFF + 9961472;           // 1024
  const size_t CNT_OFF  = PART_OFF + 1024;            // 4
  float* PRE  = (float*)(ws + PRE_OFF);
  float* EM   = (float*)(ws + EM_OFF);
  float* PART = (float*)(ws + PART_OFF);
  int*   CNT  = (int*)(ws + CNT_OFF);
  unsigned short* W3 = (unsigned short*)(ws + EM_OFF);  // consumed before k_lin writes EM
  float* out  = (float*)d_out;

  hipMemsetAsync((void*)CNT, 0, sizeof(int), stream);
  k_wprep<<<196, 256, 0, stream>>>(w_ih_f, w_ih_b, W3);
  k_ih<<<1024, 256, 0, stream>>>(x, W3, b_ih_f, b_hh_f, b_ih_b, b_hh_b, PRE);
  k_rnn<<<1024, 512, 0, stream>>>(PRE, w_hh_f, w_hh_b);
  k_lin<<<256, 256, 0, stream>>>(PRE, w_lin, b_lin, EM);
  k_crf<<<256, 128, 0, stream>>>(EM, y, st, en, trans, PART, CNT, out);
}